// Round 9
// baseline (8859.843 us; speedup 1.0000x reference)
//
#include <hip/hip_runtime.h>

#define TT 4096
#define BATCH 128
#define HID 64
#define CK 32              // checkpoint spacing
#define NCH (TT / CK)      // 128 chunks
#define NSLOT (NCH + 1)    // 129 checkpoint slots per (dir,b)
#define TG 64              // steps per l0_xg block (2 chunks)

__device__ __forceinline__ float sigm(float x) { return 1.f / (1.f + expf(-x)); }
__device__ __forceinline__ float tanh_f(float x) { float e = expf(2.f * x); return 1.f - 2.f / (e + 1.f); }

// ---------------- Kernel A: layer-0 pass, 2 threads/row, store (h,c) ckpt every CK steps ----------------
__global__ __launch_bounds__(512, 2) void lstm_ckpt(
    const float* __restrict__ x,      // [B][T][2]
    const float* __restrict__ w_ih,   // [2][256][2]
    const float* __restrict__ w_hh,   // [2][256][64]
    const float* __restrict__ b_ih, const float* __restrict__ b_hh,
    float* __restrict__ ckpt)         // [2][B][NSLOT][128] (h:0..63, c:64..127)
{
    const int blk = blockIdx.x;
    const int dir = blk & 1;
    const int b   = blk >> 1;
    const int tid = threadIdx.x;
    const int row = tid >> 1, half = tid & 1;

    __shared__ __align__(16) float xs[TT * 2];
    __shared__ __align__(16) float h_lds[HID];
    __shared__ __align__(16) float g_lds[256];

    {   // stage x[b] (32 KB)
        const float4* src = (const float4*)(x + (size_t)b * TT * 2);
        float4* dst = (float4*)xs;
        for (int rr = tid; rr < 2048; rr += 512) dst[rr] = src[rr];
    }
    const int grow = dir * 256 + row;
    float wv[32];
    {
        const float4* wr = (const float4*)(w_hh + (size_t)grow * 64) + half * 8;
        #pragma unroll
        for (int k = 0; k < 8; ++k) {
            float4 v = wr[k];
            wv[4*k] = v.x; wv[4*k+1] = v.y; wv[4*k+2] = v.z; wv[4*k+3] = v.w;
        }
    }
    const float wx0 = half ? 0.f : w_ih[grow * 2 + 0];
    const float wx1 = half ? 0.f : w_ih[grow * 2 + 1];
    const float bias = half ? 0.f : (b_ih[grow] + b_hh[grow]);
    const int gtype = row >> 6;
    float c = 0.f, hreg = 0.f;
    if (tid < HID) h_lds[tid] = 0.f;
    __syncthreads();

    for (int t = 0; t < TT; ++t) {
        const int tt = dir ? (TT - 1 - t) : t;
        if (tid < HID) {   // state BEFORE processing tt
            const int bnum = dir ? (tt + 1) : tt;
            if ((bnum & (CK - 1)) == 0) {
                float* cp = ckpt + (((size_t)(dir * BATCH + b) * NSLOT + (bnum >> 5)) << 7);
                cp[tid] = hreg; cp[HID + tid] = c;
            }
        }
        const float4* h4 = (const float4*)h_lds + half * 8;
        float a0 = 0.f, a1 = 0.f, a2 = 0.f, a3 = 0.f;
        #pragma unroll
        for (int k = 0; k < 8; ++k) {
            float4 hv = h4[k];
            a0 = fmaf(wv[4*k],   hv.x, a0);
            a1 = fmaf(wv[4*k+1], hv.y, a1);
            a2 = fmaf(wv[4*k+2], hv.z, a2);
            a3 = fmaf(wv[4*k+3], hv.w, a3);
        }
        float tot = (a0 + a1) + (a2 + a3);
        tot += __shfl_xor(tot, 1);
        if (half == 0) {
            const float acc = tot + bias + wx0 * xs[tt * 2] + wx1 * xs[tt * 2 + 1];
            g_lds[row] = (gtype == 2) ? tanh_f(acc) : sigm(acc);
        }
        __syncthreads();
        if (tid < HID) {
            const float iv = g_lds[tid], fv = g_lds[64 + tid], gg = g_lds[128 + tid], ov = g_lds[192 + tid];
            c = fv * c + iv * gg;
            hreg = ov * tanh_f(c);
            h_lds[tid] = hreg;
        }
        __syncthreads();
    }
}

// ---------------- Kernel B: PARALLEL h0 recompute (from ckpt) + xg GEMM ----------------
// grid = BATCH * (curT/TG). Block: 256 threads, one (b, 64-step group): recompute both dirs
// (2 chunks x 32 steps each, independent via ckpt) into LDS, then xg = b_ih1 + W_ih1.[h0f|h0b].
__global__ __launch_bounds__(256, 4) void l0_xg(
    const float* __restrict__ x,
    const float* __restrict__ w_ih0, const float* __restrict__ w_hh0,
    const float* __restrict__ b_ih0, const float* __restrict__ b_hh0,
    const float* __restrict__ w_ih1, const float* __restrict__ b_ih1,
    const float* __restrict__ ckpt,
    float* __restrict__ xg,           // [slabT][B][2][256]
    int slab_t0)
{
    const int ntg = gridDim.x / BATCH;
    const int b  = blockIdx.x / ntg;
    const int tg = blockIdx.x % ntg;
    const int T0 = slab_t0 + tg * TG;
    const int tid = threadIdx.x;
    const int e = tid & 63;
    const int cupd = tid >> 6;        // update role: chunk (0/1) for tid<128

    __shared__ __align__(16) float h0b[TG][128];   // 32 KB
    __shared__ __align__(16) float hs[2][64];
    __shared__ __align__(16) float gg[2][256];
    __shared__ __align__(16) float xb[TG][2];

    if (tid < 32)
        ((float4*)xb)[tid] = ((const float4*)(x + ((size_t)b * TT + T0) * 2))[tid];

    float wl0[64];
    for (int dir = 0; dir < 2; ++dir) {
        const int rowg = dir * 256 + tid;
        {
            const float4* wa = (const float4*)(w_hh0 + (size_t)rowg * 64);
            #pragma unroll
            for (int k = 0; k < 16; ++k) {
                float4 v = wa[k];
                wl0[4*k] = v.x; wl0[4*k+1] = v.y; wl0[4*k+2] = v.z; wl0[4*k+3] = v.w;
            }
        }
        const float wx0 = w_ih0[rowg * 2 + 0], wx1 = w_ih0[rowg * 2 + 1];
        const float biasr = b_ih0[rowg] + b_hh0[rowg];
        float c_st = 0.f;
        if (tid < 128) {   // load chunk state (chunk cupd)
            const int C = T0 / CK + cupd;
            const int slot = dir ? (C + 1) : C;
            const float* cp = ckpt + (((size_t)(dir * BATCH + b) * NSLOT + slot) << 7);
            hs[cupd][e] = cp[e];
            c_st = cp[HID + e];
        }
        __syncthreads();
        for (int s = 0; s < CK; ++s) {
            float res[2];
            #pragma unroll
            for (int c = 0; c < 2; ++c) {
                const float4* h4 = (const float4*)hs[c];
                float a0 = 0.f, a1 = 0.f, a2 = 0.f, a3 = 0.f;
                #pragma unroll
                for (int k = 0; k < 16; ++k) {
                    float4 hv = h4[k];
                    a0 = fmaf(wl0[4*k],   hv.x, a0);
                    a1 = fmaf(wl0[4*k+1], hv.y, a1);
                    a2 = fmaf(wl0[4*k+2], hv.z, a2);
                    a3 = fmaf(wl0[4*k+3], hv.w, a3);
                }
                const int tl = c * CK + (dir ? (CK - 1 - s) : s);
                res[c] = biasr + ((a0 + a1) + (a2 + a3)) + wx0 * xb[tl][0] + wx1 * xb[tl][1];
            }
            #pragma unroll
            for (int c = 0; c < 2; ++c)
                gg[c][tid] = ((tid >> 6) == 2) ? tanh_f(res[c]) : sigm(res[c]);
            __syncthreads();
            if (tid < 128) {
                const float iv = gg[cupd][e], fv = gg[cupd][64 + e], g2 = gg[cupd][128 + e], ov = gg[cupd][192 + e];
                c_st = fv * c_st + iv * g2;
                const float hv = ov * tanh_f(c_st);
                const int tl = cupd * CK + (dir ? (CK - 1 - s) : s);
                hs[cupd][e] = hv;
                h0b[tl][dir * 64 + e] = hv;
            }
            __syncthreads();
        }
    }
    // GEMM: xg[t][b][l1dir][r] = b_ih1 + sum_k wi1[r][k] * h0b[t][k]
    for (int l1dir = 0; l1dir < 2; ++l1dir) {
        const float4* wrow = (const float4*)(w_ih1 + (size_t)(l1dir * 256 + tid) * 128);
        const float br = b_ih1[l1dir * 256 + tid];
        for (int halfT = 0; halfT < 2; ++halfT) {
            float acc[32];
            #pragma unroll
            for (int s2 = 0; s2 < 32; ++s2) acc[s2] = br;
            for (int kq = 0; kq < 32; ++kq) {
                float4 wc = wrow[kq];
                #pragma unroll
                for (int s2 = 0; s2 < 32; ++s2) {
                    float4 hv = *(const float4*)&h0b[halfT * 32 + s2][kq * 4];
                    acc[s2] = fmaf(wc.w, hv.w, fmaf(wc.z, hv.z, fmaf(wc.y, hv.y, fmaf(wc.x, hv.x, acc[s2]))));
                }
            }
            for (int s2 = 0; s2 < 32; ++s2) {
                const int tl = halfT * 32 + s2;
                xg[(((size_t)(tg * TG + tl) * BATCH + b) * 2 + l1dir) * 256 + tid] = acc[s2];
            }
        }
    }
}

// ---------------- Kernel C: serial L1 recurrence + FC logits (slim: wl1[64] only) ----------------
// 256 blocks (b,l1dir) x 256 threads (thread = gate row). xg prefetched into LDS ring by
// two waves alternating steps (2-step load->use gap hides HBM latency).
__global__ __launch_bounds__(256, 2) void lstm_l1(
    const float* __restrict__ w_hh1, const float* __restrict__ b_hh1,
    const float* __restrict__ fc_w,
    const float* __restrict__ xg,     // [slabT][B][2][256]
    float* __restrict__ hc1,          // [256][128] carry (h,c)
    float* __restrict__ plog,         // [2][B][T][2]
    int slab_t0, int slabT)
{
    const int blk = blockIdx.x;
    const int l1dir = blk & 1;
    const int b = blk >> 1;
    const int tid = threadIdx.x;
    const int lane = tid & 63;

    __shared__ __align__(16) float h1b[2][HID];
    __shared__ __align__(16) float g1[256];
    __shared__ __align__(16) float xq[4][256];

    float wl1[64];
    {
        const int grow = l1dir * 256 + tid;
        const float4* wh = (const float4*)(w_hh1 + (size_t)grow * 64);
        #pragma unroll
        for (int k = 0; k < 16; ++k) {
            float4 v = wh[k];
            wl1[4*k] = v.x; wl1[4*k+1] = v.y; wl1[4*k+2] = v.z; wl1[4*k+3] = v.w;
        }
    }
    const float bias1 = b_hh1[l1dir * 256 + tid];
    float fw0 = 0.f, fw1 = 0.f;
    if (tid >= 64 && tid < 128) {
        fw0 = fc_w[l1dir * 64 + lane];
        fw1 = fc_w[128 + l1dir * 64 + lane];
    }
    float c1 = 0.f;
    float* hcme = hc1 + (size_t)blk * 128;
    if (tid < 64) {
        if (slab_t0 == 0) { h1b[0][tid] = 0.f; c1 = 0.f; }
        else { h1b[0][tid] = hcme[tid]; c1 = hcme[64 + tid]; }
    }
    // per-thread xg base (lane covers float4 slot)
    const float* xgb = xg + ((size_t)b * 2 + l1dir) * 256;
    const size_t tstride = (size_t)BATCH * 2 * 256;
    // prologue: prefill steps 0,1; pend loads for 2,3
    if (tid < 128) {
        const int stp = tid >> 6;
        if (stp < slabT)
            ((float4*)xq[stp])[lane] = ((const float4*)(xgb + (size_t)stp * tstride))[lane];
    }
    float4 pend = make_float4(0.f, 0.f, 0.f, 0.f);
    if (tid >= 64 && tid < 192) {
        const int tgt = (tid < 128) ? 2 : 3;
        if (tgt < slabT) pend = ((const float4*)(xgb + (size_t)tgt * tstride))[lane];
    }
    __syncthreads();

    for (int tt = 0; tt < slabT; ++tt) {
        const int u = slab_t0 + tt;
        const int cur = tt & 1;
        // ---- phase A: gate dot ----
        {
            const float4* h4 = (const float4*)h1b[cur];
            float a0 = 0.f, a1 = 0.f, a2 = 0.f, a3 = 0.f;
            #pragma unroll
            for (int k = 0; k < 16; ++k) {
                float4 hv = h4[k];
                a0 = fmaf(wl1[4*k],   hv.x, a0);
                a1 = fmaf(wl1[4*k+1], hv.y, a1);
                a2 = fmaf(wl1[4*k+2], hv.z, a2);
                a3 = fmaf(wl1[4*k+3], hv.w, a3);
            }
            const float acc = bias1 + xq[tt & 3][tid] + ((a0 + a1) + (a2 + a3));
            g1[tid] = ((tid >> 6) == 2) ? tanh_f(acc) : sigm(acc);
        }
        __syncthreads();
        // ---- phase B: update / logits / prefetch ----
        if (tid < 64) {
            const float iv = g1[tid], fv = g1[64 + tid], gg = g1[128 + tid], ov = g1[192 + tid];
            c1 = fv * c1 + iv * gg;
            h1b[cur ^ 1][tid] = ov * tanh_f(c1);
        } else if (tid < 192) {
            if (tid < 128 && u > 0) {   // logits of h after global step u-1
                const float hv = h1b[cur][lane];
                float p0 = hv * fw0, p1 = hv * fw1;
                #pragma unroll
                for (int d_ = 32; d_ > 0; d_ >>= 1) { p0 += __shfl_xor(p0, d_); p1 += __shfl_xor(p1, d_); }
                if (lane == 0) {
                    const int tp = l1dir ? (TT - u) : (u - 1);
                    *(float2*)(plog + (((size_t)l1dir * BATCH + b) * TT + tp) * 2) = make_float2(p0, p1);
                }
            }
            const int par = (tid < 128) ? 0 : 1;   // wave1 even steps, wave2 odd
            if ((tt & 1) == par) {
                if (tt + 2 < slabT) ((float4*)xq[(tt + 2) & 3])[lane] = pend;
                if (tt + 4 < slabT) pend = ((const float4*)(xgb + (size_t)(tt + 4) * tstride))[lane];
            }
        }
        __syncthreads();
    }
    if (tid < 64) { hcme[tid] = h1b[slabT & 1][tid]; hcme[64 + tid] = c1; }
    if (slab_t0 + slabT == TT && tid >= 64 && tid < 128) {   // final logits (u = TT)
        const float hv = h1b[slabT & 1][lane];
        float p0 = hv * fw0, p1 = hv * fw1;
        #pragma unroll
        for (int d_ = 32; d_ > 0; d_ >>= 1) { p0 += __shfl_xor(p0, d_); p1 += __shfl_xor(p1, d_); }
        if (lane == 0) {
            const int tp = l1dir ? 0 : (TT - 1);
            *(float2*)(plog + (((size_t)l1dir * BATCH + b) * TT + tp) * 2) = make_float2(p0, p1);
        }
    }
}

// ---------------- Kernel D: fused Viterbi (max-plus parallel scan + backtrack) ----------------
__device__ __forceinline__ unsigned long long shfl_u64(unsigned long long v, int src) {
    unsigned int lo = (unsigned int)v, hi = (unsigned int)(v >> 32);
    lo = __shfl(lo, src); hi = __shfl(hi, src);
    return ((unsigned long long)hi << 32) | lo;
}

__global__ __launch_bounds__(64, 1) void viterbi_k(
    const float* __restrict__ plog, const float* __restrict__ fc_b,
    const float* __restrict__ trans, const float* __restrict__ startv,
    const float* __restrict__ endv, int* __restrict__ out)
{
    const int b = blockIdx.x;
    const int lane = threadIdx.x;
    __shared__ __align__(16) float2 e_lds[64][65];

    const float fb0 = fc_b[0], fb1 = fc_b[1];
    const float* pf = plog + ((size_t)(0 * BATCH + b) * TT) * 2;
    const float* pb = plog + ((size_t)(1 * BATCH + b) * TT) * 2;
    for (int r = 0; r < 32; ++r) {
        const int i4 = r * 64 + lane;
        float4 a = ((const float4*)pf)[i4];
        float4 cc = ((const float4*)pb)[i4];
        const int t0 = 2 * i4, t1 = t0 + 1;
        e_lds[t0 & 63][t0 >> 6] = make_float2(a.x + cc.x + fb0, a.y + cc.y + fb1);
        e_lds[t1 & 63][t1 >> 6] = make_float2(a.z + cc.z + fb0, a.w + cc.w + fb1);
    }
    __syncthreads();
    const float tr00 = trans[0], tr01 = trans[1], tr10 = trans[2], tr11 = trans[3];
    const float2 e0 = e_lds[0][0];
    const float s00 = startv[0] + e0.x, s01 = startv[1] + e0.y;

    const int lo = lane * 64;
    const int hi = (lane == 63) ? (TT - 1) : (lo + 64);
    float a00, a01, a10, a11;
    {
        const float2 ee = e_lds[(lo + 1) & 63][(lo + 1) >> 6];
        a00 = tr00 + ee.x; a01 = tr01 + ee.y; a10 = tr10 + ee.x; a11 = tr11 + ee.y;
    }
    for (int t = lo + 2; t <= hi; ++t) {
        const float2 ee = e_lds[t & 63][t >> 6];
        const float n00 = fmaxf(a00 + tr00, a01 + tr10) + ee.x;
        const float n01 = fmaxf(a00 + tr01, a01 + tr11) + ee.y;
        const float n10 = fmaxf(a10 + tr00, a11 + tr10) + ee.x;
        const float n11 = fmaxf(a10 + tr01, a11 + tr11) + ee.y;
        a00 = n00; a01 = n01; a10 = n10; a11 = n11;
    }
    #pragma unroll
    for (int d = 1; d < 64; d <<= 1) {
        const float o00 = __shfl_up(a00, d), o01 = __shfl_up(a01, d);
        const float o10 = __shfl_up(a10, d), o11 = __shfl_up(a11, d);
        if (lane >= d) {
            const float n00 = fmaxf(o00 + a00, o01 + a10);
            const float n01 = fmaxf(o00 + a01, o01 + a11);
            const float n10 = fmaxf(o10 + a00, o11 + a10);
            const float n11 = fmaxf(o10 + a01, o11 + a11);
            a00 = n00; a01 = n01; a10 = n10; a11 = n11;
        }
    }
    const float p00 = __shfl_up(a00, 1), p01 = __shfl_up(a01, 1);
    const float p10 = __shfl_up(a10, 1), p11 = __shfl_up(a11, 1);
    float s0, s1;
    if (lane == 0) { s0 = s00; s1 = s01; }
    else { s0 = fmaxf(s00 + p00, s01 + p10); s1 = fmaxf(s00 + p01, s01 + p11); }
    unsigned long long m0 = 0ull, m1 = 0ull;
    for (int t = lo + 1; t <= hi; ++t) {
        const float2 ee = e_lds[t & 63][t >> 6];
        const float c00 = s0 + tr00, c10 = s1 + tr10;
        const float c01 = s0 + tr01, c11 = s1 + tr11;
        const int bp0 = c10 > c00, bp1 = c11 > c01;
        s0 = (bp0 ? c10 : c00) + ee.x;
        s1 = (bp1 ? c11 : c01) + ee.y;
        m0 |= (unsigned long long)bp0 << (t - lo - 1);
        m1 |= (unsigned long long)bp1 << (t - lo - 1);
    }
    int last;
    {
        const int lt = (s1 + endv[1]) > (s0 + endv[0]);
        last = __shfl(lt, 63);
    }
    int f0 = 0, f1 = 1;
    for (int t = hi; t > lo; --t) {
        const int s_ = t - lo - 1;
        f0 = (int)(((f0 ? m1 : m0) >> s_) & 1ull);
        f1 = (int)(((f1 ? m1 : m0) >> s_) & 1ull);
    }
    int mm = f0 | (f1 << 1);
    #pragma unroll
    for (int d = 1; d < 64; d <<= 1) {
        const int mo = __shfl_down(mm, d);
        if (lane + d < 64) {
            const int r0 = (mm >> (mo & 1)) & 1;
            const int r1_ = (mm >> ((mo >> 1) & 1)) & 1;
            mm = r0 | (r1_ << 1);
        }
    }
    const int gn = __shfl_down(mm, 1);
    int cur = (lane == 63) ? last : ((gn >> last) & 1);
    unsigned long long tagm = 0ull;
    if (lane == 63) tagm |= (unsigned long long)last << 63;
    for (int t = hi; t > lo; --t) {
        const int s_ = t - lo - 1;
        cur = (int)(((cur ? m1 : m0) >> s_) & 1ull);
        tagm |= (unsigned long long)cur << s_;
    }
    int* ob = out + (size_t)b * TT;
    for (int r = 0; r < 64; ++r) {
        const unsigned long long mr = shfl_u64(tagm, r);
        ob[r * 64 + lane] = (int)((mr >> lane) & 1ull);
    }
}

extern "C" void kernel_launch(void* const* d_in, const int* in_sizes, int n_in,
                              void* d_out, int out_size, void* d_ws, size_t ws_size,
                              hipStream_t stream) {
    const float* x      = (const float*)d_in[0];
    const float* w_ih0  = (const float*)d_in[1];
    const float* w_hh0  = (const float*)d_in[2];
    const float* b_ih0  = (const float*)d_in[3];
    const float* b_hh0  = (const float*)d_in[4];
    const float* w_ih1  = (const float*)d_in[5];
    const float* w_hh1  = (const float*)d_in[6];
    const float* b_ih1  = (const float*)d_in[7];
    const float* b_hh1  = (const float*)d_in[8];
    const float* fc_w   = (const float*)d_in[9];
    const float* fc_b   = (const float*)d_in[10];
    const float* trans  = (const float*)d_in[11];
    const float* startv = (const float*)d_in[12];
    const float* endv   = (const float*)d_in[13];

    char* ws = (char*)d_ws;
    const size_t ckpt_bytes = (size_t)2 * BATCH * NSLOT * 128 * 4;   // ~16.9 MB
    const size_t plog_bytes = (size_t)2 * BATCH * TT * 2 * 4;        // 8 MB
    const size_t hc1_bytes  = (size_t)256 * 128 * 4;                 // 128 KB
    float* ckpt = (float*)ws;
    float* plog = (float*)(ws + ckpt_bytes);
    float* hc1  = (float*)(ws + ckpt_bytes + plog_bytes);
    float* xg   = (float*)(ws + ckpt_bytes + plog_bytes + hc1_bytes);

    // adaptive slab size from workspace
    const size_t perT = (size_t)BATCH * 2 * 256 * 4;                 // 256 KB per step
    const size_t fixed = ckpt_bytes + plog_bytes + hc1_bytes;
    size_t avail = (ws_size > fixed) ? (ws_size - fixed) : 0;
    int slabT = (int)(avail / perT);
    slabT = (slabT / TG) * TG;
    if (slabT > TT) slabT = TT;
    if (slabT < TG) slabT = TG;

    lstm_ckpt<<<256, 512, 0, stream>>>(x, w_ih0, w_hh0, b_ih0, b_hh0, ckpt);
    for (int t0 = 0; t0 < TT; t0 += slabT) {
        const int curT = (TT - t0 < slabT) ? (TT - t0) : slabT;
        l0_xg<<<BATCH * (curT / TG), 256, 0, stream>>>(x, w_ih0, w_hh0, b_ih0, b_hh0,
                                                       w_ih1, b_ih1, ckpt, xg, t0);
        lstm_l1<<<256, 256, 0, stream>>>(w_hh1, b_hh1, fc_w, xg, hc1, plog, t0, curT);
    }
    viterbi_k<<<128, 64, 0, stream>>>(plog, fc_b, trans, startv, endv, (int*)d_out);
}